// Round 10
// baseline (46.803 us; speedup 1.0000x reference)
//
#include <hip/hip_runtime.h>

// Degrade: per-sample depthwise 13x13 cross-correlation, stride 4,
// replicate padding p=6.  im: [8,4,1024,1024] f32, kernel: [8,1,13,13] f32,
// out: [8,4,256,256] f32.
//
// R9: R8's structure (scatter-partial cooperative conv, ky-phase
// compile-time decomposition, scalar wave-id, interior/edge block
// specialization, per-phase load batching, 3-shfl end combine) with
// TH 4 -> 8: vertical register reuse doubles, total VMEM lane-addresses
// drop 16.4M -> 13.4M (the 6-round-fit cost model: ~1 lane-addr/cyc/CU
// -> 22 us).  R6's TH=8 failed on branchy structure + VGPR cap, both
// fixed since.  5120 waves, no launch_bounds min-wave cap.

#define KS 13
#define IH 1024
#define IW 1024
#define OH 256
#define OW 256
#define WOX 61              // valid outputs per wave in x (3-lane halo)
#define TH 8                // output rows per thread
#define NROWS (4 * TH + 9)  // 41 input rows per thread
#define NU 11               // max rows per ky-phase = ceil(41/4)

__device__ __forceinline__ float pick_c(const float4& x, int s) {
    float a = (s & 2) ? x.z : x.x;
    float b = (s & 2) ? x.w : x.y;
    return (s & 1) ? b : a;
}

template <bool EDGE>
__device__ __forceinline__ void conv_body(
    const float* __restrict__ pl, const float* __restrict__ kb,
    int gy0, int fbase, int cb, int s0, int s1, int s2, int s3,
    bool interior, float acc[TH][4])
{
    // 4 phases: rows t === r (mod 4) share compile-time ky set
#pragma unroll
    for (int r = 0; r < 4; ++r) {
        float4 x[NU];
        // ---- load batch: all rows of this phase ----
#pragma unroll
        for (int u = 0; u < NU; ++u) {
            const int t = r + 4 * u;               // compile-time
            if (t < NROWS) {
                const int gy = min(max(gy0 + t, 0), IH - 1);   // scalar
                const float* __restrict__ row = pl + (size_t)gy * IW;
                if (EDGE) {
                    float4 raw = *(const float4*)(row + cb);
                    if (!interior) {
                        float4 f;
                        f.x = pick_c(raw, s0); f.y = pick_c(raw, s1);
                        f.z = pick_c(raw, s2); f.w = pick_c(raw, s3);
                        raw = f;
                    }
                    x[u] = raw;
                } else {
                    x[u] = *(const float4*)(row + fbase);
                }
            }
        }
        // ---- FMA batch ----
#pragma unroll
        for (int u = 0; u < NU; ++u) {
            const int t = r + 4 * u;
            if (t < NROWS) {
#pragma unroll
                for (int ky = r; ky < KS; ky += 4) {
                    const int j = (t - ky) >> 2;   // compile-time
                    if (j >= 0 && j < TH) {
                        const float* __restrict__ kr = kb + ky * KS;
                        const float4& v = x[u];
                        // chunk float c -> tap kx=4p+c-2 of output (lane-p)
                        acc[j][0] = fmaf(v.z, kr[0],  acc[j][0]);
                        acc[j][0] = fmaf(v.w, kr[1],  acc[j][0]);
                        acc[j][1] = fmaf(v.x, kr[2],  acc[j][1]);
                        acc[j][1] = fmaf(v.y, kr[3],  acc[j][1]);
                        acc[j][1] = fmaf(v.z, kr[4],  acc[j][1]);
                        acc[j][1] = fmaf(v.w, kr[5],  acc[j][1]);
                        acc[j][2] = fmaf(v.x, kr[6],  acc[j][2]);
                        acc[j][2] = fmaf(v.y, kr[7],  acc[j][2]);
                        acc[j][2] = fmaf(v.z, kr[8],  acc[j][2]);
                        acc[j][2] = fmaf(v.w, kr[9],  acc[j][2]);
                        acc[j][3] = fmaf(v.x, kr[10], acc[j][3]);
                        acc[j][3] = fmaf(v.y, kr[11], acc[j][3]);
                        acc[j][3] = fmaf(v.z, kr[12], acc[j][3]);
                    }
                }
            }
        }
    }
}

__global__ __launch_bounds__(256) void degrade_kernel(
    const float* __restrict__ im,
    const float* __restrict__ kern,
    float* __restrict__ out)
{
    const int plane = blockIdx.z;          // b*4 + c
    const int b     = plane >> 2;
    const int tid   = threadIdx.x;
    const int lane  = tid & 63;
    // wave id: uniform across the wave's 64 lanes -> force SGPR
    const int w     = __builtin_amdgcn_readfirstlane(tid >> 6);
    const int ox0   = blockIdx.x * WOX;
    const int oy0   = blockIdx.y * (4 * TH) + w * TH;   // scalar

    const float* __restrict__ pl = im + (size_t)plane * (IH * IW);
    const float* __restrict__ kb = kern + b * (KS * KS);   // wave-uniform

    // this lane's 16B chunk: floats fbase..fbase+3 of each input row
    const int fbase = 4 * ox0 - 8 + 4 * lane;
    const int cb    = min(max(fbase, 0), IW - 4);
    const bool interior = (fbase == cb);
    const int s0 = min(max(fbase + 0, 0), IW - 1) - cb;
    const int s1 = min(max(fbase + 1, 0), IW - 1) - cb;
    const int s2 = min(max(fbase + 2, 0), IW - 1) - cb;
    const int s3 = min(max(fbase + 3, 0), IW - 1) - cb;

    const int gy0 = 4 * oy0 - 6;           // scalar

    float acc[TH][4];
#pragma unroll
    for (int j = 0; j < TH; ++j)
#pragma unroll
        for (int p = 0; p < 4; ++p) acc[j][p] = 0.0f;

    // blocks 1..gridDim.x-2 are provably interior (fbase in [236,979])
    if (blockIdx.x == 0 || blockIdx.x == gridDim.x - 1)
        conv_body<true >(pl, kb, gy0, fbase, cb, s0, s1, s2, s3, interior, acc);
    else
        conv_body<false>(pl, kb, gy0, fbase, cb, s0, s1, s2, s3, interior, acc);

    // combine partials across lanes (once) and store
    const bool valid = (lane < WOX) && (ox0 + lane < OW);
#pragma unroll
    for (int j = 0; j < TH; ++j) {
        float v = acc[j][0]
                + __shfl(acc[j][1], lane + 1, 64)
                + __shfl(acc[j][2], lane + 2, 64)
                + __shfl(acc[j][3], lane + 3, 64);
        if (valid)
            out[((size_t)plane * OH + oy0 + j) * OW + ox0 + lane] = v;
    }
}

extern "C" void kernel_launch(void* const* d_in, const int* in_sizes, int n_in,
                              void* d_out, int out_size, void* d_ws, size_t ws_size,
                              hipStream_t stream)
{
    const float* im   = (const float*)d_in[0];
    const float* kern = (const float*)d_in[1];
    float* out        = (float*)d_out;

    dim3 grid((OW + WOX - 1) / WOX,    // 5
              OH / (4 * TH),           // 8
              32);                     // 1280 blocks = 5120 waves
    degrade_kernel<<<grid, 256, 0, stream>>>(im, kern, out);
}

// Round 11
// 41.099 us; speedup vs baseline: 1.1388x; 1.1388x over previous
//
#include <hip/hip_runtime.h>

// Degrade: per-sample depthwise 13x13 cross-correlation, stride 4,
// replicate padding p=6.  im: [8,4,1024,1024] f32, kernel: [8,1,13,13] f32,
// out: [8,4,256,256] f32.
//
// R10: R8 skeleton (scatter-partial cooperative conv, ky-phase compile-time
// decomposition, scalar wave-id, interior/edge block specialization, 3-shfl
// end combine, TH=4, 10240 waves) + DEPTH-2 SOFTWARE PIPELINE across the 4
// ky-phases: two named load register sets xA/xB, interleaved
//   loadA(0) loadB(1) fmaA(0) loadA(2) fmaB(1) loadB(3) fmaA(2) fmaB(3)
// The compiler's counted s_waitcnt vmcnt(N) keeps ~7 loads in flight while
// FMAing the previous phase (R8 drained each phase before computing ->
// latency-bound; R9 refuted the lane-address-throughput model).

#define KS 13
#define IH 1024
#define IW 1024
#define OH 256
#define OW 256
#define WOX 61              // valid outputs per wave in x (3-lane halo)
#define TH 4                // output rows per thread
#define NROWS (4 * TH + 9)  // 25 input rows per thread

__device__ __forceinline__ float pick_c(const float4& x, int s) {
    float a = (s & 2) ? x.z : x.x;
    float b = (s & 2) ? x.w : x.y;
    return (s & 1) ? b : a;
}

// ---- load all rows of ky-phase R (t = R + 4u) into x[7] ----
template <int R, bool EDGE>
__device__ __forceinline__ void load_phase(
    float4 (&x)[7], const float* __restrict__ pl,
    int gy0, int fbase, int cb, int s0, int s1, int s2, int s3, bool interior)
{
#pragma unroll
    for (int u = 0; u < 7; ++u) {
        const int t = R + 4 * u;                   // compile-time
        if (t < NROWS) {
            const int gy = min(max(gy0 + t, 0), IH - 1);   // scalar
            const float* __restrict__ row = pl + (size_t)gy * IW;
            if (EDGE) {
                float4 raw = *(const float4*)(row + cb);
                if (!interior) {
                    float4 f;
                    f.x = pick_c(raw, s0); f.y = pick_c(raw, s1);
                    f.z = pick_c(raw, s2); f.w = pick_c(raw, s3);
                    raw = f;
                }
                x[u] = raw;
            } else {
                x[u] = *(const float4*)(row + fbase);
            }
        }
    }
}

// ---- FMA all rows of ky-phase R against the partial accumulators ----
template <int R>
__device__ __forceinline__ void fma_phase(
    const float4 (&x)[7], const float* __restrict__ kb, float acc[TH][4])
{
#pragma unroll
    for (int u = 0; u < 7; ++u) {
        const int t = R + 4 * u;                   // compile-time
        if (t < NROWS) {
#pragma unroll
            for (int ky = R; ky < KS; ky += 4) {
                const int j = (t - ky) >> 2;       // compile-time
                if (j >= 0 && j < TH) {
                    const float* __restrict__ kr = kb + ky * KS;
                    const float4& v = x[u];
                    // chunk float c -> tap kx=4p+c-2 of output (lane-p)
                    acc[j][0] = fmaf(v.z, kr[0],  acc[j][0]);
                    acc[j][0] = fmaf(v.w, kr[1],  acc[j][0]);
                    acc[j][1] = fmaf(v.x, kr[2],  acc[j][1]);
                    acc[j][1] = fmaf(v.y, kr[3],  acc[j][1]);
                    acc[j][1] = fmaf(v.z, kr[4],  acc[j][1]);
                    acc[j][1] = fmaf(v.w, kr[5],  acc[j][1]);
                    acc[j][2] = fmaf(v.x, kr[6],  acc[j][2]);
                    acc[j][2] = fmaf(v.y, kr[7],  acc[j][2]);
                    acc[j][2] = fmaf(v.z, kr[8],  acc[j][2]);
                    acc[j][2] = fmaf(v.w, kr[9],  acc[j][2]);
                    acc[j][3] = fmaf(v.x, kr[10], acc[j][3]);
                    acc[j][3] = fmaf(v.y, kr[11], acc[j][3]);
                    acc[j][3] = fmaf(v.z, kr[12], acc[j][3]);
                }
            }
        }
    }
}

template <bool EDGE>
__device__ __forceinline__ void conv_body(
    const float* __restrict__ pl, const float* __restrict__ kb,
    int gy0, int fbase, int cb, int s0, int s1, int s2, int s3,
    bool interior, float acc[TH][4])
{
    float4 xA[7], xB[7];
    // depth-2 pipeline: phase r+1's loads in flight during phase r's FMAs
    load_phase<0, EDGE>(xA, pl, gy0, fbase, cb, s0, s1, s2, s3, interior);
    load_phase<1, EDGE>(xB, pl, gy0, fbase, cb, s0, s1, s2, s3, interior);
    fma_phase<0>(xA, kb, acc);
    load_phase<2, EDGE>(xA, pl, gy0, fbase, cb, s0, s1, s2, s3, interior);
    fma_phase<1>(xB, kb, acc);
    load_phase<3, EDGE>(xB, pl, gy0, fbase, cb, s0, s1, s2, s3, interior);
    fma_phase<2>(xA, kb, acc);
    fma_phase<3>(xB, kb, acc);
}

__global__ __launch_bounds__(256) void degrade_kernel(
    const float* __restrict__ im,
    const float* __restrict__ kern,
    float* __restrict__ out)
{
    const int plane = blockIdx.z;          // b*4 + c
    const int b     = plane >> 2;
    const int tid   = threadIdx.x;
    const int lane  = tid & 63;
    // wave id: uniform across the wave's 64 lanes -> force SGPR
    const int w     = __builtin_amdgcn_readfirstlane(tid >> 6);
    const int ox0   = blockIdx.x * WOX;
    const int oy0   = blockIdx.y * (4 * TH) + w * TH;   // scalar

    const float* __restrict__ pl = im + (size_t)plane * (IH * IW);
    const float* __restrict__ kb = kern + b * (KS * KS);   // wave-uniform

    // this lane's 16B chunk: floats fbase..fbase+3 of each input row
    const int fbase = 4 * ox0 - 8 + 4 * lane;
    const int cb    = min(max(fbase, 0), IW - 4);
    const bool interior = (fbase == cb);
    const int s0 = min(max(fbase + 0, 0), IW - 1) - cb;
    const int s1 = min(max(fbase + 1, 0), IW - 1) - cb;
    const int s2 = min(max(fbase + 2, 0), IW - 1) - cb;
    const int s3 = min(max(fbase + 3, 0), IW - 1) - cb;

    const int gy0 = 4 * oy0 - 6;           // scalar

    float acc[TH][4];
#pragma unroll
    for (int j = 0; j < TH; ++j)
#pragma unroll
        for (int p = 0; p < 4; ++p) acc[j][p] = 0.0f;

    // blocks 1..gridDim.x-2 are provably interior (fbase in [236,979])
    if (blockIdx.x == 0 || blockIdx.x == gridDim.x - 1)
        conv_body<true >(pl, kb, gy0, fbase, cb, s0, s1, s2, s3, interior, acc);
    else
        conv_body<false>(pl, kb, gy0, fbase, cb, s0, s1, s2, s3, interior, acc);

    // combine partials across lanes (once) and store
    const bool valid = (lane < WOX) && (ox0 + lane < OW);
#pragma unroll
    for (int j = 0; j < TH; ++j) {
        float v = acc[j][0]
                + __shfl(acc[j][1], lane + 1, 64)
                + __shfl(acc[j][2], lane + 2, 64)
                + __shfl(acc[j][3], lane + 3, 64);
        if (valid)
            out[((size_t)plane * OH + oy0 + j) * OW + ox0 + lane] = v;
    }
}

extern "C" void kernel_launch(void* const* d_in, const int* in_sizes, int n_in,
                              void* d_out, int out_size, void* d_ws, size_t ws_size,
                              hipStream_t stream)
{
    const float* im   = (const float*)d_in[0];
    const float* kern = (const float*)d_in[1];
    float* out        = (float*)d_out;

    dim3 grid((OW + WOX - 1) / WOX,    // 5
              OH / (4 * TH),           // 16
              32);                     // 2560 blocks = 10240 waves
    degrade_kernel<<<grid, 256, 0, stream>>>(im, kern, out);
}

// Round 12
// 36.352 us; speedup vs baseline: 1.2875x; 1.1306x over previous
//
#include <hip/hip_runtime.h>

// Degrade: per-sample depthwise 13x13 cross-correlation, stride 4,
// replicate padding p=6.  im: [8,4,1024,1024] f32, kernel: [8,1,13,13] f32,
// out: [8,4,256,256] f32.
//
// R11 = R8 body (best: 40.4us) + XCD-aware y-contiguous block remap.
// R8's L1-ingress = 262 MB / 40.4us = 6.55 TB/s = 10.7 B/cyc/CU == the
// measured per-CU global-load streaming ceiling.  46% of that traffic is
// vertical re-read shared with y-adjacent blocks, which round-robin onto
// DIFFERENT XCDs today (y-stride 5 in flat id).  1-D grid + bijective
// decode puts each XCD on a y-fastest column walk: overlap rows become
// same-XCD L2 hits instead of cross-die L3/HBM refetches.
//   h -> lid = (h&7)*320 + (h>>3);  y=lid&15, x=(lid>>4)%5, z=lid/80.

#define KS 13
#define IH 1024
#define IW 1024
#define OH 256
#define OW 256
#define WOX 61              // valid outputs per wave in x (3-lane halo)
#define TH 4                // output rows per thread
#define NROWS (4 * TH + 9)  // 25 input rows per thread
#define GRIDX 5
#define GRIDY 16
#define GRIDZ 32
#define NWG (GRIDX * GRIDY * GRIDZ)     // 2560, divisible by 8 XCDs
#define PERX (NWG / 8)                  // 320 blocks per XCD chunk

__device__ __forceinline__ float pick_c(const float4& x, int s) {
    float a = (s & 2) ? x.z : x.x;
    float b = (s & 2) ? x.w : x.y;
    return (s & 1) ? b : a;
}

template <bool EDGE>
__device__ __forceinline__ void conv_body(
    const float* __restrict__ pl, const float* __restrict__ kb,
    int gy0, int fbase, int cb, int s0, int s1, int s2, int s3,
    bool interior, float acc[TH][4])
{
    // 4 phases: rows t === r (mod 4) share compile-time ky set
#pragma unroll
    for (int r = 0; r < 4; ++r) {
        float4 x[7];
        // ---- load batch: all rows of this phase (MLP ~7) ----
#pragma unroll
        for (int u = 0; u < 7; ++u) {
            const int t = r + 4 * u;               // compile-time
            if (t < NROWS) {
                const int gy = min(max(gy0 + t, 0), IH - 1);   // scalar
                const float* __restrict__ row = pl + (size_t)gy * IW;
                if (EDGE) {
                    float4 raw = *(const float4*)(row + cb);
                    if (!interior) {
                        float4 f;
                        f.x = pick_c(raw, s0); f.y = pick_c(raw, s1);
                        f.z = pick_c(raw, s2); f.w = pick_c(raw, s3);
                        raw = f;
                    }
                    x[u] = raw;
                } else {
                    x[u] = *(const float4*)(row + fbase);
                }
            }
        }
        // ---- FMA batch ----
#pragma unroll
        for (int u = 0; u < 7; ++u) {
            const int t = r + 4 * u;
            if (t < NROWS) {
#pragma unroll
                for (int ky = r; ky < KS; ky += 4) {
                    const int j = (t - ky) >> 2;   // compile-time
                    if (j >= 0 && j < TH) {
                        const float* __restrict__ kr = kb + ky * KS;
                        const float4& v = x[u];
                        // chunk float c -> tap kx=4p+c-2 of output (lane-p)
                        acc[j][0] = fmaf(v.z, kr[0],  acc[j][0]);
                        acc[j][0] = fmaf(v.w, kr[1],  acc[j][0]);
                        acc[j][1] = fmaf(v.x, kr[2],  acc[j][1]);
                        acc[j][1] = fmaf(v.y, kr[3],  acc[j][1]);
                        acc[j][1] = fmaf(v.z, kr[4],  acc[j][1]);
                        acc[j][1] = fmaf(v.w, kr[5],  acc[j][1]);
                        acc[j][2] = fmaf(v.x, kr[6],  acc[j][2]);
                        acc[j][2] = fmaf(v.y, kr[7],  acc[j][2]);
                        acc[j][2] = fmaf(v.z, kr[8],  acc[j][2]);
                        acc[j][2] = fmaf(v.w, kr[9],  acc[j][2]);
                        acc[j][3] = fmaf(v.x, kr[10], acc[j][3]);
                        acc[j][3] = fmaf(v.y, kr[11], acc[j][3]);
                        acc[j][3] = fmaf(v.z, kr[12], acc[j][3]);
                    }
                }
            }
        }
    }
}

__global__ __launch_bounds__(256) void degrade_kernel(
    const float* __restrict__ im,
    const float* __restrict__ kern,
    float* __restrict__ out)
{
    // ---- XCD-aware decode: y-adjacent logical blocks share an XCD ----
    const int h   = blockIdx.x;                    // round-robins XCDs
    const int lid = (h & 7) * PERX + (h >> 3);     // bijective remap
    const int by  = lid & 15;                      // y fastest
    const int tXZ = lid >> 4;
    const int bx  = tXZ % GRIDX;
    const int bz  = tXZ / GRIDX;

    const int plane = bz;                  // b*4 + c
    const int b     = plane >> 2;
    const int tid   = threadIdx.x;
    const int lane  = tid & 63;
    const int w     = __builtin_amdgcn_readfirstlane(tid >> 6);
    const int ox0   = bx * WOX;
    const int oy0   = by * (4 * TH) + w * TH;      // scalar

    const float* __restrict__ pl = im + (size_t)plane * (IH * IW);
    const float* __restrict__ kb = kern + b * (KS * KS);   // wave-uniform

    // this lane's 16B chunk: floats fbase..fbase+3 of each input row
    const int fbase = 4 * ox0 - 8 + 4 * lane;
    const int cb    = min(max(fbase, 0), IW - 4);
    const bool interior = (fbase == cb);
    const int s0 = min(max(fbase + 0, 0), IW - 1) - cb;
    const int s1 = min(max(fbase + 1, 0), IW - 1) - cb;
    const int s2 = min(max(fbase + 2, 0), IW - 1) - cb;
    const int s3 = min(max(fbase + 3, 0), IW - 1) - cb;

    const int gy0 = 4 * oy0 - 6;           // scalar

    float acc[TH][4];
#pragma unroll
    for (int j = 0; j < TH; ++j)
#pragma unroll
        for (int p = 0; p < 4; ++p) acc[j][p] = 0.0f;

    // blocks bx=1..3 are provably interior (fbase in [236,979])
    if (bx == 0 || bx == GRIDX - 1)
        conv_body<true >(pl, kb, gy0, fbase, cb, s0, s1, s2, s3, interior, acc);
    else
        conv_body<false>(pl, kb, gy0, fbase, cb, s0, s1, s2, s3, interior, acc);

    // combine partials across lanes (once) and store
    const bool valid = (lane < WOX) && (ox0 + lane < OW);
#pragma unroll
    for (int j = 0; j < TH; ++j) {
        float v = acc[j][0]
                + __shfl(acc[j][1], lane + 1, 64)
                + __shfl(acc[j][2], lane + 2, 64)
                + __shfl(acc[j][3], lane + 3, 64);
        if (valid)
            out[((size_t)plane * OH + oy0 + j) * OW + ox0 + lane] = v;
    }
}

extern "C" void kernel_launch(void* const* d_in, const int* in_sizes, int n_in,
                              void* d_out, int out_size, void* d_ws, size_t ws_size,
                              hipStream_t stream)
{
    const float* im   = (const float*)d_in[0];
    const float* kern = (const float*)d_in[1];
    float* out        = (float*)d_out;

    degrade_kernel<<<dim3(NWG, 1, 1), 256, 0, stream>>>(im, kern, out);
}

// Round 13
// 29.684 us; speedup vs baseline: 1.5767x; 1.2246x over previous
//
#include <hip/hip_runtime.h>

// Degrade: per-sample depthwise 13x13 cross-correlation, stride 4,
// replicate padding p=6.  im: [8,4,1024,1024] f32, kernel: [8,1,13,13] f32,
// out: [8,4,256,256] f32.
//
// R12 = R11 (36.4us: scatter-partial cooperative conv + ky-phase
// compile-time decomposition + XCD plane-per-die remap) with FULL-DEPTH
// load pipelining: all 25 row loads issued up front (phase-major) into
// x[25], order pinned with sched_barrier(0), consumed in issue order so
// the compiler emits progressive counted vmcnt waits.  Outstanding
// loads/wave 7 -> 25 (Little's law: forces the memory system to its real
// ceiling instead of 4 serial latency-exposed phases per wave).
// Edge fixup moved to the consume side so edge blocks don't serialize
// the load burst.

#define KS 13
#define IH 1024
#define IW 1024
#define OH 256
#define OW 256
#define WOX 61              // valid outputs per wave in x (3-lane halo)
#define TH 4                // output rows per thread
#define NROWS (4 * TH + 9)  // 25 input rows per thread
#define GRIDX 5
#define GRIDY 16
#define GRIDZ 32
#define NWG (GRIDX * GRIDY * GRIDZ)     // 2560, divisible by 8 XCDs
#define PERX (NWG / 8)                  // 320 blocks per XCD chunk

__device__ __forceinline__ float pick_c(const float4& x, int s) {
    float a = (s & 2) ? x.z : x.x;
    float b = (s & 2) ? x.w : x.y;
    return (s & 1) ? b : a;
}

template <bool EDGE>
__device__ __forceinline__ void conv_body(
    const float* __restrict__ pl, const float* __restrict__ kb,
    int gy0, int fbase, int cb, int s0, int s1, int s2, int s3,
    bool interior, float acc[TH][4])
{
    float4 x[NROWS];          // 100 VGPR; all indices compile-time

    // ---- issue ALL row loads, phase-major (t = r + 4u) ----
    {
        int c = 0;            // folds to constants under full unroll
#pragma unroll
        for (int r = 0; r < 4; ++r) {
#pragma unroll
            for (int u = 0; u < 7; ++u) {
                const int t = r + 4 * u;
                if (t < NROWS) {
                    const int gy = min(max(gy0 + t, 0), IH - 1);  // scalar
                    const float* __restrict__ row = pl + (size_t)gy * IW;
                    x[c] = *(const float4*)(row + (EDGE ? cb : fbase));
                    ++c;
                }
            }
        }
    }
    // pin the load burst above the FMA section (compiler would otherwise
    // sink loads to just-before-use, collapsing MLP back to ~7)
    __builtin_amdgcn_sched_barrier(0);

    // ---- consume in issue order: progressive vmcnt waits ----
    {
        int c = 0;
#pragma unroll
        for (int r = 0; r < 4; ++r) {
#pragma unroll
            for (int u = 0; u < 7; ++u) {
                const int t = r + 4 * u;
                if (t < NROWS) {
                    float4 v = x[c]; ++c;
                    if (EDGE) {
                        if (!interior) {          // border lanes only
                            float4 f;
                            f.x = pick_c(v, s0); f.y = pick_c(v, s1);
                            f.z = pick_c(v, s2); f.w = pick_c(v, s3);
                            v = f;
                        }
                    }
#pragma unroll
                    for (int ky = r; ky < KS; ky += 4) {
                        const int j = (t - ky) >> 2;   // compile-time
                        if (j >= 0 && j < TH) {
                            const float* __restrict__ kr = kb + ky * KS;
                            // chunk float c -> tap kx=4p+c-2 of out (lane-p)
                            acc[j][0] = fmaf(v.z, kr[0],  acc[j][0]);
                            acc[j][0] = fmaf(v.w, kr[1],  acc[j][0]);
                            acc[j][1] = fmaf(v.x, kr[2],  acc[j][1]);
                            acc[j][1] = fmaf(v.y, kr[3],  acc[j][1]);
                            acc[j][1] = fmaf(v.z, kr[4],  acc[j][1]);
                            acc[j][1] = fmaf(v.w, kr[5],  acc[j][1]);
                            acc[j][2] = fmaf(v.x, kr[6],  acc[j][2]);
                            acc[j][2] = fmaf(v.y, kr[7],  acc[j][2]);
                            acc[j][2] = fmaf(v.z, kr[8],  acc[j][2]);
                            acc[j][2] = fmaf(v.w, kr[9],  acc[j][2]);
                            acc[j][3] = fmaf(v.x, kr[10], acc[j][3]);
                            acc[j][3] = fmaf(v.y, kr[11], acc[j][3]);
                            acc[j][3] = fmaf(v.z, kr[12], acc[j][3]);
                        }
                    }
                }
            }
        }
    }
}

__global__ __launch_bounds__(256) void degrade_kernel(
    const float* __restrict__ im,
    const float* __restrict__ kern,
    float* __restrict__ out)
{
    // ---- XCD-aware decode: y-adjacent blocks + whole planes per XCD ----
    const int h   = blockIdx.x;                    // round-robins XCDs
    const int lid = (h & 7) * PERX + (h >> 3);     // bijective remap
    const int by  = lid & 15;                      // y fastest
    const int tXZ = lid >> 4;
    const int bx  = tXZ % GRIDX;
    const int bz  = tXZ / GRIDX;

    const int plane = bz;                  // b*4 + c
    const int b     = plane >> 2;
    const int tid   = threadIdx.x;
    const int lane  = tid & 63;
    const int w     = __builtin_amdgcn_readfirstlane(tid >> 6);
    const int ox0   = bx * WOX;
    const int oy0   = by * (4 * TH) + w * TH;      // scalar

    const float* __restrict__ pl = im + (size_t)plane * (IH * IW);
    const float* __restrict__ kb = kern + b * (KS * KS);   // wave-uniform

    // this lane's 16B chunk: floats fbase..fbase+3 of each input row
    const int fbase = 4 * ox0 - 8 + 4 * lane;
    const int cb    = min(max(fbase, 0), IW - 4);
    const bool interior = (fbase == cb);
    const int s0 = min(max(fbase + 0, 0), IW - 1) - cb;
    const int s1 = min(max(fbase + 1, 0), IW - 1) - cb;
    const int s2 = min(max(fbase + 2, 0), IW - 1) - cb;
    const int s3 = min(max(fbase + 3, 0), IW - 1) - cb;

    const int gy0 = 4 * oy0 - 6;           // scalar

    float acc[TH][4];
#pragma unroll
    for (int j = 0; j < TH; ++j)
#pragma unroll
        for (int p = 0; p < 4; ++p) acc[j][p] = 0.0f;

    // blocks bx=1..3 are provably interior (fbase in [236,979])
    if (bx == 0 || bx == GRIDX - 1)
        conv_body<true >(pl, kb, gy0, fbase, cb, s0, s1, s2, s3, interior, acc);
    else
        conv_body<false>(pl, kb, gy0, fbase, cb, s0, s1, s2, s3, interior, acc);

    // combine partials across lanes (once) and store
    const bool valid = (lane < WOX) && (ox0 + lane < OW);
#pragma unroll
    for (int j = 0; j < TH; ++j) {
        float v = acc[j][0]
                + __shfl(acc[j][1], lane + 1, 64)
                + __shfl(acc[j][2], lane + 2, 64)
                + __shfl(acc[j][3], lane + 3, 64);
        if (valid)
            out[((size_t)plane * OH + oy0 + j) * OW + ox0 + lane] = v;
    }
}

extern "C" void kernel_launch(void* const* d_in, const int* in_sizes, int n_in,
                              void* d_out, int out_size, void* d_ws, size_t ws_size,
                              hipStream_t stream)
{
    const float* im   = (const float*)d_in[0];
    const float* kern = (const float*)d_in[1];
    float* out        = (float*)d_out;

    degrade_kernel<<<dim3(NWG, 1, 1), 256, 0, stream>>>(im, kern, out);
}